// Round 8
// baseline (361.010 us; speedup 1.0000x reference)
//
#include <hip/hip_runtime.h>
#include <hip/hip_bf16.h>

#define TDIM 2048
#define DDIM 768
#define IDIM 2048
#define NEXP 8

typedef __bf16 v8bf __attribute__((ext_vector_type(8)));
typedef float v4f __attribute__((ext_vector_type(4)));
typedef int   v4i __attribute__((ext_vector_type(4)));
typedef float v4ff __attribute__((ext_vector_type(4)));

#define MFMA_B16(A,B,C) __builtin_amdgcn_mfma_f32_16x16x32_bf16(A,B,C,0,0,0)

typedef __attribute__((address_space(1))) const unsigned int* gas_t;
typedef __attribute__((address_space(3))) unsigned int* las_t;

__device__ __forceinline__ void gload16(const void* g, void* l) {
  __builtin_amdgcn_global_load_lds((gas_t)g, (las_t)l, 16, 0, 0);
}

__device__ __forceinline__ v8bf cvt_i(v4i a0, v4i a1) {
  v8bf v;
  v[0] = (__bf16)(float)a0[0]; v[1] = (__bf16)(float)a0[1];
  v[2] = (__bf16)(float)a0[2]; v[3] = (__bf16)(float)a0[3];
  v[4] = (__bf16)(float)a1[0]; v[5] = (__bf16)(float)a1[1];
  v[6] = (__bf16)(float)a1[2]; v[7] = (__bf16)(float)a1[3];
  return v;
}
__device__ __forceinline__ v8bf cvt_f(v4ff a0, v4ff a1) {
  v8bf v;
  v[0] = (__bf16)a0[0]; v[1] = (__bf16)a0[1]; v[2] = (__bf16)a0[2]; v[3] = (__bf16)a0[3];
  v[4] = (__bf16)a1[0]; v[5] = (__bf16)a1[1]; v[6] = (__bf16)a1[2]; v[7] = (__bf16)a1[3];
  return v;
}

// ================= merged router + x-pack + weight-pack =================
// Pack strategy: CONTIGUOUS READS, XOR-scattered 16B writes (full 128B windows).
// blocks [0,512):       router, 4 tokens/block (1/wave); wt premultiplied by sd[e]
// blocks [512,1280):    x fp32 -> bf16 (linear)
// blocks [1280,3328):   expert gate/up: e=(pb>>8), T=(pb>>7)&1, blk16=pb&127
//                       16 source rows/block; combined row rg=(r>>4)*32+(r&15)+T*16
// blocks [3328,3584):   shared gate/up
// blocks [3584,4352):   expert down: e=pb/96, blk8=pb%96; 8 source rows/block
// blocks [4352,4448):   shared down
// Tile format (unchanged from r7): tile=16384B, dst(row, cb) holds source chunk
// at byte (cb ^ ((row&7)<<4)); GEMM reads with the same XOR.
__global__ __launch_bounds__(256)
void pack_all_kernel(const int* __restrict__ qg, const int* __restrict__ qu,
                     const int* __restrict__ qd,
                     const float* __restrict__ sg, const float* __restrict__ su,
                     const float* __restrict__ sd, const float* __restrict__ x,
                     const float* __restrict__ rw, const float* __restrict__ es,
                     __hip_bfloat16* __restrict__ wguT, __hip_bfloat16* __restrict__ sguT,
                     __hip_bfloat16* __restrict__ wdT,  __hip_bfloat16* __restrict__ sdT,
                     __hip_bfloat16* __restrict__ xb,
                     int* __restrict__ cnt, int* __restrict__ lists, float* __restrict__ wt)
{
  const int b = blockIdx.x;
  const int tid = threadIdx.x;

  if (b < 512) {  // ---------------- router ----------------
    const int t = b * 4 + (tid >> 6);
    const int lane = tid & 63;
    const float* xp = x + (size_t)t * DDIM;
    float4 xv0 = *(const float4*)(xp + lane * 4);
    float4 xv1 = *(const float4*)(xp + 256 + lane * 4);
    float4 xv2 = *(const float4*)(xp + 512 + lane * 4);
    float logit[NEXP];
#pragma unroll
    for (int e = 0; e < NEXP; ++e) {
      const float* w = rw + (size_t)e * DDIM;
      float4 w0 = *(const float4*)(w + lane * 4);
      float4 w1 = *(const float4*)(w + 256 + lane * 4);
      float4 w2 = *(const float4*)(w + 512 + lane * 4);
      float p = xv0.x * w0.x + xv0.y * w0.y + xv0.z * w0.z + xv0.w * w0.w
              + xv1.x * w1.x + xv1.y * w1.y + xv1.z * w1.z + xv1.w * w1.w
              + xv2.x * w2.x + xv2.y * w2.y + xv2.z * w2.z + xv2.w * w2.w;
#pragma unroll
      for (int off = 32; off > 0; off >>= 1) p += __shfl_down(p, off, 64);
      logit[e] = p;
    }
    if (lane == 0) {
      float m = logit[0];
#pragma unroll
      for (int e = 1; e < NEXP; ++e) m = fmaxf(m, logit[e]);
      float pr[NEXP];
#pragma unroll
      for (int e = 0; e < NEXP; ++e) pr[e] = expf(logit[e] - m);
      int i0 = 0; float v0 = pr[0];
#pragma unroll
      for (int e = 1; e < NEXP; ++e) if (pr[e] > v0) { v0 = pr[e]; i0 = e; }
      int i1 = -1; float v1 = -1.f;
#pragma unroll
      for (int e = 0; e < NEXP; ++e) if (e != i0 && pr[e] > v1) { v1 = pr[e]; i1 = e; }
      float inv = 1.f / (v0 + v1);
      int p0 = atomicAdd(&cnt[i0], 1);
      lists[i0 * TDIM + p0] = t * 2;       // slot = t*2 + k
      wt[t * 2] = v0 * inv * es[i0 * 3 + 2];        // gate weight * down-scale
      int p1 = atomicAdd(&cnt[i1], 1);
      lists[i1 * TDIM + p1] = t * 2 + 1;
      wt[t * 2 + 1] = v1 * inv * es[i1 * 3 + 2];
    }
    return;
  }

  if (b < 1280) {  // ---------------- x fp32 -> bf16 ----------------
    const size_t i = (size_t)(b - 512) * 2048 + tid * 8;
    float4 a0 = *(const float4*)(x + i);
    float4 a1 = *(const float4*)(x + i + 4);
    v8bf v;
    v[0] = (__bf16)a0.x; v[1] = (__bf16)a0.y; v[2] = (__bf16)a0.z; v[3] = (__bf16)a0.w;
    v[4] = (__bf16)a1.x; v[5] = (__bf16)a1.y; v[6] = (__bf16)a1.z; v[7] = (__bf16)a1.w;
    *(v8bf*)(xb + i) = v;
    return;
  }

  if (b < 3584) {  // ---------------- paired gate+up pack ----------------
    const int pb = b - 1280;
    const int* isrc = nullptr; const float* fsrc = nullptr;
    char* dstT;
    int T, blk16, isint;
    if (pb < 2048) {
      const int e = pb >> 8; T = (pb >> 7) & 1; blk16 = pb & 127;
      isrc = (T ? qu : qg) + (size_t)e * IDIM * DDIM;
      dstT = (char*)wguT + (size_t)e * 32 * 12 * 16384;
      isint = 1;
    } else {
      const int sb = pb - 2048;
      T = sb >> 7; blk16 = sb & 127;
      fsrc = T ? su : sg;
      dstT = (char*)sguT;
      isint = 0;
    }
    const int srcrow  = blk16 * 16 + (tid >> 4);       // [0, 2048)
    const int colbase = (tid & 15) * 48;               // 48 elems/thread = 192B
    const int rg = ((srcrow >> 4) * 32) + (srcrow & 15) + T * 16;
    const int tnt = rg >> 7, rowin = rg & 127;
    const int xorm = (rowin & 7) << 4;
    char* rowdst = dstT + (size_t)tnt * 12 * 16384 + rowin * 128;
    const size_t soff = (size_t)srcrow * DDIM + colbase;

    if (isint) {
      v4i r[12];
      const v4i* sp = (const v4i*)(isrc + soff);
#pragma unroll
      for (int i = 0; i < 12; ++i) r[i] = sp[i];
#pragma unroll
      for (int g = 0; g < 6; ++g) {
        const int col = colbase + g * 8;
        const int kt = col >> 6, c = (col >> 3) & 7;
        *(v8bf*)(rowdst + (size_t)kt * 16384 + ((c * 16) ^ xorm)) = cvt_i(r[2 * g], r[2 * g + 1]);
      }
    } else {
      v4ff r[12];
      const v4ff* sp = (const v4ff*)(fsrc + soff);
#pragma unroll
      for (int i = 0; i < 12; ++i) r[i] = sp[i];
#pragma unroll
      for (int g = 0; g < 6; ++g) {
        const int col = colbase + g * 8;
        const int kt = col >> 6, c = (col >> 3) & 7;
        *(v8bf*)(rowdst + (size_t)kt * 16384 + ((c * 16) ^ xorm)) = cvt_f(r[2 * g], r[2 * g + 1]);
      }
    }
    return;
  }

  // ---------------- down pack ----------------
  {
    const int pb = b - 3584;
    const int* isrc = nullptr; const float* fsrc = nullptr;
    char* dstT;
    int blk8, isint;
    if (pb < 768) {
      const int e = pb / 96; blk8 = pb % 96;
      isrc = qd + (size_t)e * DDIM * IDIM;
      dstT = (char*)wdT + (size_t)e * 192 * 16384;
      isint = 1;
    } else {
      blk8 = pb - 768;
      fsrc = sd;
      dstT = (char*)sdT;
      isint = 0;
    }
    const int srcrow = blk8 * 8 + (tid >> 5);          // [0, 768)
    const int kt = tid & 31;                           // one full 64-elem strip
    const int tnt = srcrow >> 7, rowin = srcrow & 127;
    const int xorm = (rowin & 7) << 4;
    char* rowdst = dstT + ((size_t)tnt * 32 + kt) * 16384 + rowin * 128;
    const size_t soff = (size_t)srcrow * IDIM + kt * 64;

    if (isint) {
      v4i r[16];
      const v4i* sp = (const v4i*)(isrc + soff);
#pragma unroll
      for (int i = 0; i < 16; ++i) r[i] = sp[i];
#pragma unroll
      for (int c = 0; c < 8; ++c)
        *(v8bf*)(rowdst + ((c * 16) ^ xorm)) = cvt_i(r[2 * c], r[2 * c + 1]);
    } else {
      v4ff r[16];
      const v4ff* sp = (const v4ff*)(fsrc + soff);
#pragma unroll
      for (int i = 0; i < 16; ++i) r[i] = sp[i];
#pragma unroll
      for (int c = 0; c < 8; ++c)
        *(v8bf*)(rowdst + ((c * 16) ^ xorm)) = cvt_f(r[2 * c], r[2 * c + 1]);
    }
  }
}

// ================= gate+up GEMM, 128x128 tile, N=4096 interleaved =================
// blocks [0,4096): experts (e=b>>9, tm=(b>>5)&15, tn=b&31), gathered rows
// blocks [4096,4608): shared expert, dense rows (h rows 4096+t)
// acc[4][4]: fragment pairs (2p,2p+1) hold (gate,up) for the SAME i -> in-register silu.
__global__ __launch_bounds__(256, 3)
void gu_gemm_kernel(const __hip_bfloat16* __restrict__ xb,
                    const __hip_bfloat16* __restrict__ wguT, const __hip_bfloat16* __restrict__ sguT,
                    const float* __restrict__ es,
                    const int* __restrict__ cnt, const int* __restrict__ lists,
                    __hip_bfloat16* __restrict__ h)
{
  const int b = blockIdx.x;
  int tm, tn, count;
  const char* bbase;
  const int* listE = nullptr;
  float sgc, suc;
  if (b < 4096) {
    const int e = b >> 9; tm = (b >> 5) & 15; tn = b & 31;
    count = cnt[e];
    if (tm * 128 >= count) return;
    bbase = (const char*)wguT + (size_t)(e * 32 + tn) * (12 * 16384);
    listE = lists + e * TDIM;
    sgc = es[e * 3 + 0]; suc = es[e * 3 + 1];
  } else {
    const int b2 = b - 4096; tm = b2 >> 5; tn = b2 & 31;
    count = TDIM;
    bbase = (const char*)sguT + (size_t)tn * (12 * 16384);
    sgc = 1.f; suc = 1.f;
  }

  __shared__ __align__(16) char As[16384];
  __shared__ __align__(16) char Bs[16384];

  const int tid = threadIdx.x;
  const int lane = tid & 63;
  const int wid = tid >> 6;
  const int wr = wid >> 1, wc = wid & 1;
  const int lr16 = lane & 15, hk = lane >> 4;

  const int cA = (((lane & 7) ^ (lane >> 3)) << 4);
  const char* aptr[4];
#pragma unroll
  for (int p = 0; p < 4; ++p) {
    const int row = p * 32 + wid * 8 + (lane >> 3);
    const int rg = tm * 128 + row;
    int tok;
    if (listE) { const int idx = rg < count ? rg : count - 1; tok = listE[idx] >> 1; }
    else tok = rg;
    aptr[p] = (const char*)xb + (size_t)tok * (DDIM * 2) + cA;
  }
  const char* bp = bbase + wid * 1024 + lane * 16;

  v4f acc[4][4] = {};

  for (int kt = 0; kt < 12; ++kt) {
#pragma unroll
    for (int p = 0; p < 4; ++p) gload16(aptr[p] + kt * 128, As + wid * 1024 + p * 4096);
#pragma unroll
    for (int p = 0; p < 4; ++p) gload16(bp + kt * 16384 + p * 4096, Bs + wid * 1024 + p * 4096);
    __syncthreads();
#pragma unroll
    for (int ks = 0; ks < 2; ++ks) {
      const int colb = ks * 64 + hk * 16;
      v8bf fa[4], fb[4];
#pragma unroll
      for (int m = 0; m < 4; ++m) {
        const int r = wr * 64 + m * 16 + lr16;
        fa[m] = *(const v8bf*)(As + r * 128 + (colb ^ ((r & 7) << 4)));
      }
#pragma unroll
      for (int n = 0; n < 4; ++n) {
        const int r = wc * 64 + n * 16 + lr16;
        fb[n] = *(const v8bf*)(Bs + r * 128 + (colb ^ ((r & 7) << 4)));
      }
#pragma unroll
      for (int n = 0; n < 4; ++n)
#pragma unroll
        for (int m = 0; m < 4; ++m) acc[m][n] = MFMA_B16(fa[m], fb[n], acc[m][n]);
    }
    __syncthreads();
  }

  // epilogue: pairs (2p,2p+1) = (g,u) for i = (tn*4 + wc*2 + p)*16 + lr16
#pragma unroll
  for (int m = 0; m < 4; ++m) {
#pragma unroll
    for (int j = 0; j < 4; ++j) {
      const int rl = wr * 64 + m * 16 + hk * 4 + j;
      const int rg = tm * 128 + rl;
      if (rg >= count) continue;
      const size_t drow = listE ? (size_t)listE[rg] : (size_t)(4096 + rg);
      __hip_bfloat16* dh = h + drow * IDIM + (tn * 4 + wc * 2) * 16 + lr16;
#pragma unroll
      for (int p = 0; p < 2; ++p) {
        const float g = acc[m][2 * p][j] * sgc;
        const float u = acc[m][2 * p + 1][j] * suc;
        dh[p * 16] = __float2bfloat16(g / (1.f + __expf(-g)) * u);
      }
    }
  }
}

// ================= down GEMM, 128x128 tile, K=2048, atomicAdd into out =================
// blocks [0,768): experts (e=b/96, tm=(b%96)/6, tn=b%6), A = h[slot]
// blocks [768,864): shared expert, A = h[4096+t]
__global__ __launch_bounds__(256, 3)
void down_kernel(const __hip_bfloat16* __restrict__ h,
                 const __hip_bfloat16* __restrict__ wdT, const __hip_bfloat16* __restrict__ sdT,
                 const float* __restrict__ wt,
                 const int* __restrict__ cnt, const int* __restrict__ lists,
                 float* __restrict__ out)
{
  const int b = blockIdx.x;
  int tm, tn, count;
  const char* bbase;
  const int* listE = nullptr;
  if (b < 768) {
    const int e = b / 96; const int r = b % 96; tm = r / 6; tn = r % 6;
    count = cnt[e];
    if (tm * 128 >= count) return;
    bbase = (const char*)wdT + (size_t)(e * 6 + tn) * (32 * 16384);
    listE = lists + e * TDIM;
  } else {
    const int r = b - 768; tm = r / 6; tn = r % 6;
    count = TDIM;
    bbase = (const char*)sdT + (size_t)tn * (32 * 16384);
  }

  __shared__ __align__(16) char As[16384];
  __shared__ __align__(16) char Bs[16384];

  const int tid = threadIdx.x;
  const int lane = tid & 63;
  const int wid = tid >> 6;
  const int wr = wid >> 1, wc = wid & 1;
  const int lr16 = lane & 15, hk = lane >> 4;

  const int cA = (((lane & 7) ^ (lane >> 3)) << 4);
  const char* aptr[4];
#pragma unroll
  for (int p = 0; p < 4; ++p) {
    const int row = p * 32 + wid * 8 + (lane >> 3);
    const int rg = tm * 128 + row;
    int srow;
    if (listE) { const int idx = rg < count ? rg : count - 1; srow = listE[idx]; }
    else srow = 4096 + rg;
    aptr[p] = (const char*)h + (size_t)srow * (IDIM * 2) + cA;
  }
  const char* bp = bbase + wid * 1024 + lane * 16;

  v4f acc[4][4] = {};

  for (int kt = 0; kt < 32; ++kt) {
#pragma unroll
    for (int p = 0; p < 4; ++p) gload16(aptr[p] + kt * 128, As + wid * 1024 + p * 4096);
#pragma unroll
    for (int p = 0; p < 4; ++p) gload16(bp + kt * 16384 + p * 4096, Bs + wid * 1024 + p * 4096);
    __syncthreads();
#pragma unroll
    for (int ks = 0; ks < 2; ++ks) {
      const int colb = ks * 64 + hk * 16;
      v8bf fa[4], fb[4];
#pragma unroll
      for (int m = 0; m < 4; ++m) {
        const int r = wr * 64 + m * 16 + lr16;
        fa[m] = *(const v8bf*)(As + r * 128 + (colb ^ ((r & 7) << 4)));
      }
#pragma unroll
      for (int n = 0; n < 4; ++n) {
        const int r = wc * 64 + n * 16 + lr16;
        fb[n] = *(const v8bf*)(Bs + r * 128 + (colb ^ ((r & 7) << 4)));
      }
#pragma unroll
      for (int n = 0; n < 4; ++n)
#pragma unroll
        for (int m = 0; m < 4; ++m) acc[m][n] = MFMA_B16(fa[m], fb[n], acc[m][n]);
    }
    __syncthreads();
  }

#pragma unroll
  for (int m = 0; m < 4; ++m) {
#pragma unroll
    for (int j = 0; j < 4; ++j) {
      const int rl = wr * 64 + m * 16 + hk * 4 + j;
      const int rg = tm * 128 + rl;
      if (rg >= count) continue;
      int tok; float w;
      if (listE) { const int slot = listE[rg]; tok = slot >> 1; w = wt[slot]; }  // wt pre-multiplied by sd
      else { tok = rg; w = 1.f; }
      float* dst = out + (size_t)tok * DDIM + tn * 128 + wc * 64 + lr16;
#pragma unroll
      for (int n = 0; n < 4; ++n) atomicAdd(dst + n * 16, acc[m][n][j] * w);
    }
  }
}

extern "C" void kernel_launch(void* const* d_in, const int* in_sizes, int n_in,
                              void* d_out, int out_size, void* d_ws, size_t ws_size,
                              hipStream_t stream)
{
  const float* x   = (const float*)d_in[0];
  const float* rw  = (const float*)d_in[1];
  const float* swg = (const float*)d_in[2];
  const float* swu = (const float*)d_in[3];
  const float* swd = (const float*)d_in[4];
  const int*   qg  = (const int*)d_in[5];
  const int*   qu  = (const int*)d_in[6];
  const int*   qd  = (const int*)d_in[7];
  const float* es  = (const float*)d_in[8];
  float* out = (float*)d_out;

  char* ws = (char*)d_ws;
  size_t off = 0;
  auto alloc = [&](size_t bytes) { void* p = ws + off; off = (off + bytes + 255) & ~(size_t)255; return p; };
  // total ws usage ~= 113 MB
  int*   cnt   = (int*)alloc(NEXP * 4);
  int*   lists = (int*)alloc((size_t)NEXP * TDIM * 4);
  float* wt    = (float*)alloc((size_t)2 * TDIM * 4);
  __hip_bfloat16* xb   = (__hip_bfloat16*)alloc((size_t)TDIM * DDIM * 2);
  __hip_bfloat16* wguT = (__hip_bfloat16*)alloc((size_t)NEXP * 32 * 12 * 8192 * 2);
  __hip_bfloat16* sguT = (__hip_bfloat16*)alloc((size_t)32 * 12 * 8192 * 2);
  __hip_bfloat16* wdT  = (__hip_bfloat16*)alloc((size_t)NEXP * 6 * 32 * 8192 * 2);
  __hip_bfloat16* sdT  = (__hip_bfloat16*)alloc((size_t)6 * 32 * 8192 * 2);
  __hip_bfloat16* h    = (__hip_bfloat16*)alloc((size_t)(4096 + TDIM) * IDIM * 2);

  hipMemsetAsync(cnt, 0, NEXP * 4, stream);
  hipMemsetAsync(out, 0, (size_t)TDIM * DDIM * 4, stream);

  pack_all_kernel<<<4448, 256, 0, stream>>>(qg, qu, qd, swg, swu, swd, x, rw, es,
                                            wguT, sguT, wdT, sdT, xb, cnt, lists, wt);
  gu_gemm_kernel<<<4096 + 512, 256, 0, stream>>>(xb, wguT, sguT, es, cnt, lists, h);
  down_kernel<<<768 + 96, 256, 0, stream>>>(h, wdT, sdT, wt, cnt, lists, out);
}

// Round 9
// 351.372 us; speedup vs baseline: 1.0274x; 1.0274x over previous
//
#include <hip/hip_runtime.h>
#include <hip/hip_bf16.h>

#define TDIM 2048
#define DDIM 768
#define IDIM 2048
#define NEXP 8

typedef __bf16 v8bf __attribute__((ext_vector_type(8)));
typedef __bf16 v4bf __attribute__((ext_vector_type(4)));
typedef float v4f __attribute__((ext_vector_type(4)));
typedef int   v4i __attribute__((ext_vector_type(4)));
typedef float v4ff __attribute__((ext_vector_type(4)));

#define MFMA_B16(A,B,C) __builtin_amdgcn_mfma_f32_16x16x32_bf16(A,B,C,0,0,0)

typedef __attribute__((address_space(1))) const unsigned int* gas_t;
typedef __attribute__((address_space(3))) unsigned int* las_t;

__device__ __forceinline__ void gload16(const void* g, void* l) {
  __builtin_amdgcn_global_load_lds((gas_t)g, (las_t)l, 16, 0, 0);
}

__device__ __forceinline__ v4bf cvt4_i(v4i a) {
  v4bf v;
  v[0] = (__bf16)(float)a[0]; v[1] = (__bf16)(float)a[1];
  v[2] = (__bf16)(float)a[2]; v[3] = (__bf16)(float)a[3];
  return v;
}
__device__ __forceinline__ v4bf cvt4_f(v4ff a) {
  v4bf v;
  v[0] = (__bf16)a[0]; v[1] = (__bf16)a[1]; v[2] = (__bf16)a[2]; v[3] = (__bf16)a[3];
  return v;
}

// ================= merged router + x-pack + weight-pack =================
// Pack strategy v3: PER-INSTRUCTION lane-sequential loads (lane l reads 16B at
// base + l*16 within a row-segment), XOR swizzle applied on the 8B STORE position
// (within-128B-window permutation -> store lines still fully covered).
// Thread unit: 16B source (4 elems) -> 8B bf16 dst. 8 source rows per block,
// lanes 0-31 on row (tid>>5)... loads hoisted 6-8 deep for MLP.
// blocks [0,512):      router, 4 tokens/block (1/wave); wt premultiplied by sd[e]
// blocks [512,768):    x fp32 -> bf16 (linear), 8 rows/block
// blocks [768,4864):   expert gate/up: e=pb>>9, T=(pb>>8)&1, r8=pb&255 (8 rows)
// blocks [4864,5376):  shared gate/up: T=pb>>8, r8=pb&255
// blocks [5376,6144):  expert down: e=pb/96, r8=pb%96
// blocks [6144,6240):  shared down
// Tile format (unchanged, GEMM-verified): tile=16384B, combined gu row
// rg=(srcrow>>4)*32+(srcrow&15)+T*16; dst byte (row,cb) holds source at cb^((row&7)<<4).
__global__ __launch_bounds__(256)
void pack_all_kernel(const int* __restrict__ qg, const int* __restrict__ qu,
                     const int* __restrict__ qd,
                     const float* __restrict__ sg, const float* __restrict__ su,
                     const float* __restrict__ sd, const float* __restrict__ x,
                     const float* __restrict__ rw, const float* __restrict__ es,
                     __hip_bfloat16* __restrict__ wguT, __hip_bfloat16* __restrict__ sguT,
                     __hip_bfloat16* __restrict__ wdT,  __hip_bfloat16* __restrict__ sdT,
                     __hip_bfloat16* __restrict__ xb,
                     int* __restrict__ cnt, int* __restrict__ lists, float* __restrict__ wt)
{
  const int b = blockIdx.x;
  const int tid = threadIdx.x;

  if (b < 512) {  // ---------------- router ----------------
    const int t = b * 4 + (tid >> 6);
    const int lane = tid & 63;
    const float* xp = x + (size_t)t * DDIM;
    float4 xv0 = *(const float4*)(xp + lane * 4);
    float4 xv1 = *(const float4*)(xp + 256 + lane * 4);
    float4 xv2 = *(const float4*)(xp + 512 + lane * 4);
    float logit[NEXP];
#pragma unroll
    for (int e = 0; e < NEXP; ++e) {
      const float* w = rw + (size_t)e * DDIM;
      float4 w0 = *(const float4*)(w + lane * 4);
      float4 w1 = *(const float4*)(w + 256 + lane * 4);
      float4 w2 = *(const float4*)(w + 512 + lane * 4);
      float p = xv0.x * w0.x + xv0.y * w0.y + xv0.z * w0.z + xv0.w * w0.w
              + xv1.x * w1.x + xv1.y * w1.y + xv1.z * w1.z + xv1.w * w1.w
              + xv2.x * w2.x + xv2.y * w2.y + xv2.z * w2.z + xv2.w * w2.w;
#pragma unroll
      for (int off = 32; off > 0; off >>= 1) p += __shfl_down(p, off, 64);
      logit[e] = p;
    }
    if (lane == 0) {
      float m = logit[0];
#pragma unroll
      for (int e = 1; e < NEXP; ++e) m = fmaxf(m, logit[e]);
      float pr[NEXP];
#pragma unroll
      for (int e = 0; e < NEXP; ++e) pr[e] = expf(logit[e] - m);
      int i0 = 0; float v0 = pr[0];
#pragma unroll
      for (int e = 1; e < NEXP; ++e) if (pr[e] > v0) { v0 = pr[e]; i0 = e; }
      int i1 = -1; float v1 = -1.f;
#pragma unroll
      for (int e = 0; e < NEXP; ++e) if (e != i0 && pr[e] > v1) { v1 = pr[e]; i1 = e; }
      float inv = 1.f / (v0 + v1);
      int p0 = atomicAdd(&cnt[i0], 1);
      lists[i0 * TDIM + p0] = t * 2;       // slot = t*2 + k
      wt[t * 2] = v0 * inv * es[i0 * 3 + 2];        // gate weight * down-scale
      int p1 = atomicAdd(&cnt[i1], 1);
      lists[i1 * TDIM + p1] = t * 2 + 1;
      wt[t * 2 + 1] = v1 * inv * es[i1 * 3 + 2];
    }
    return;
  }

  const int lc = tid & 31;          // lane-column: 16B unit within row segment
  const int rowloc = tid >> 5;      // 8 rows per block

  if (b < 768) {  // ---------------- x fp32 -> bf16 (linear) ----------------
    const int row = (b - 512) * 8 + rowloc;
    const float* sp = x + (size_t)row * DDIM;
    __hip_bfloat16* dp = xb + (size_t)row * DDIM;
    v4ff r[6];
#pragma unroll
    for (int i = 0; i < 6; ++i) r[i] = *(const v4ff*)(sp + (lc + i * 32) * 4);
#pragma unroll
    for (int i = 0; i < 6; ++i) *(v4bf*)(dp + (lc + i * 32) * 4) = cvt4_f(r[i]);
    return;
  }

  if (b < 5376) {  // ---------------- gate/up pack (expert + shared) ----------------
    const int pb = b - 768;
    const int* isrc = nullptr; const float* fsrc = nullptr;
    char* dstT; int T, r8, isint;
    if (pb < 4096) {
      const int e = pb >> 9; T = (pb >> 8) & 1; r8 = pb & 255;
      isrc = (T ? qu : qg) + (size_t)e * IDIM * DDIM;
      dstT = (char*)wguT + (size_t)e * 32 * 12 * 16384;
      isint = 1;
    } else {
      const int sb = pb - 4096; T = sb >> 8; r8 = sb & 255;
      fsrc = T ? su : sg;
      dstT = (char*)sguT;
      isint = 0;
    }
    const int srcrow = r8 * 8 + rowloc;                 // [0,2048)
    const int rg = ((srcrow >> 4) * 32) + (srcrow & 15) + T * 16;
    const int tnt = rg >> 7, rowin = rg & 127;
    const int xorm = (rowin & 7) << 4;
    char* rowdst = dstT + (size_t)tnt * (12 * 16384) + rowin * 128;
    const size_t soff = (size_t)srcrow * DDIM;

    if (isint) {
      v4i r[6];
#pragma unroll
      for (int i = 0; i < 6; ++i) r[i] = *(const v4i*)(isrc + soff + (lc + i * 32) * 4);
#pragma unroll
      for (int i = 0; i < 6; ++i) {
        const int c4 = lc + i * 32;                     // [0,192)
        const int kt = c4 >> 4;
        *(v4bf*)(rowdst + (size_t)kt * 16384 + (((c4 & 15) << 3) ^ xorm)) = cvt4_i(r[i]);
      }
    } else {
      v4ff r[6];
#pragma unroll
      for (int i = 0; i < 6; ++i) r[i] = *(const v4ff*)(fsrc + soff + (lc + i * 32) * 4);
#pragma unroll
      for (int i = 0; i < 6; ++i) {
        const int c4 = lc + i * 32;
        const int kt = c4 >> 4;
        *(v4bf*)(rowdst + (size_t)kt * 16384 + (((c4 & 15) << 3) ^ xorm)) = cvt4_f(r[i]);
      }
    }
    return;
  }

  // ---------------- down pack (expert + shared) ----------------
  {
    const int pb = b - 5376;
    const int* isrc = nullptr; const float* fsrc = nullptr;
    char* dstT; int r8, isint;
    if (pb < 768) {
      const int e = pb / 96; r8 = pb % 96;
      isrc = qd + (size_t)e * DDIM * IDIM;
      dstT = (char*)wdT + (size_t)e * (192 * 16384);
      isint = 1;
    } else {
      r8 = pb - 768;
      fsrc = sd;
      dstT = (char*)sdT;
      isint = 0;
    }
    const int srcrow = r8 * 8 + rowloc;                 // [0,768)
    const int tnt = srcrow >> 7, rowin = srcrow & 127;
    const int xorm = (rowin & 7) << 4;
    char* rowdst = dstT + (size_t)tnt * (32 * 16384) + rowin * 128;
    const size_t soff = (size_t)srcrow * IDIM;

#pragma unroll
    for (int h = 0; h < 2; ++h) {
      if (isint) {
        v4i r[8];
#pragma unroll
        for (int j = 0; j < 8; ++j) r[j] = *(const v4i*)(isrc + soff + (lc + (h * 8 + j) * 32) * 4);
#pragma unroll
        for (int j = 0; j < 8; ++j) {
          const int c4 = lc + (h * 8 + j) * 32;         // [0,512)
          const int kt = c4 >> 4;
          *(v4bf*)(rowdst + (size_t)kt * 16384 + (((c4 & 15) << 3) ^ xorm)) = cvt4_i(r[j]);
        }
      } else {
        v4ff r[8];
#pragma unroll
        for (int j = 0; j < 8; ++j) r[j] = *(const v4ff*)(fsrc + soff + (lc + (h * 8 + j) * 32) * 4);
#pragma unroll
        for (int j = 0; j < 8; ++j) {
          const int c4 = lc + (h * 8 + j) * 32;
          const int kt = c4 >> 4;
          *(v4bf*)(rowdst + (size_t)kt * 16384 + (((c4 & 15) << 3) ^ xorm)) = cvt4_f(r[j]);
        }
      }
    }
  }
}

// ================= gate+up GEMM, 128x128 tile, N=4096 interleaved =================
// blocks [0,4096): experts (e=b>>9, tm=(b>>5)&15, tn=b&31), gathered rows
// blocks [4096,4608): shared expert, dense rows (h rows 4096+t)
// acc[4][4]: fragment pairs (2p,2p+1) hold (gate,up) for the SAME i -> in-register silu.
__global__ __launch_bounds__(256, 3)
void gu_gemm_kernel(const __hip_bfloat16* __restrict__ xb,
                    const __hip_bfloat16* __restrict__ wguT, const __hip_bfloat16* __restrict__ sguT,
                    const float* __restrict__ es,
                    const int* __restrict__ cnt, const int* __restrict__ lists,
                    __hip_bfloat16* __restrict__ h)
{
  const int b = blockIdx.x;
  int tm, tn, count;
  const char* bbase;
  const int* listE = nullptr;
  float sgc, suc;
  if (b < 4096) {
    const int e = b >> 9; tm = (b >> 5) & 15; tn = b & 31;
    count = cnt[e];
    if (tm * 128 >= count) return;
    bbase = (const char*)wguT + (size_t)(e * 32 + tn) * (12 * 16384);
    listE = lists + e * TDIM;
    sgc = es[e * 3 + 0]; suc = es[e * 3 + 1];
  } else {
    const int b2 = b - 4096; tm = b2 >> 5; tn = b2 & 31;
    count = TDIM;
    bbase = (const char*)sguT + (size_t)tn * (12 * 16384);
    sgc = 1.f; suc = 1.f;
  }

  __shared__ __align__(16) char As[16384];
  __shared__ __align__(16) char Bs[16384];

  const int tid = threadIdx.x;
  const int lane = tid & 63;
  const int wid = tid >> 6;
  const int wr = wid >> 1, wc = wid & 1;
  const int lr16 = lane & 15, hk = lane >> 4;

  const int cA = (((lane & 7) ^ (lane >> 3)) << 4);
  const char* aptr[4];
#pragma unroll
  for (int p = 0; p < 4; ++p) {
    const int row = p * 32 + wid * 8 + (lane >> 3);
    const int rg = tm * 128 + row;
    int tok;
    if (listE) { const int idx = rg < count ? rg : count - 1; tok = listE[idx] >> 1; }
    else tok = rg;
    aptr[p] = (const char*)xb + (size_t)tok * (DDIM * 2) + cA;
  }
  const char* bp = bbase + wid * 1024 + lane * 16;

  v4f acc[4][4] = {};

  for (int kt = 0; kt < 12; ++kt) {
#pragma unroll
    for (int p = 0; p < 4; ++p) gload16(aptr[p] + kt * 128, As + wid * 1024 + p * 4096);
#pragma unroll
    for (int p = 0; p < 4; ++p) gload16(bp + kt * 16384 + p * 4096, Bs + wid * 1024 + p * 4096);
    __syncthreads();
#pragma unroll
    for (int ks = 0; ks < 2; ++ks) {
      const int colb = ks * 64 + hk * 16;
      v8bf fa[4], fb[4];
#pragma unroll
      for (int m = 0; m < 4; ++m) {
        const int r = wr * 64 + m * 16 + lr16;
        fa[m] = *(const v8bf*)(As + r * 128 + (colb ^ ((r & 7) << 4)));
      }
#pragma unroll
      for (int n = 0; n < 4; ++n) {
        const int r = wc * 64 + n * 16 + lr16;
        fb[n] = *(const v8bf*)(Bs + r * 128 + (colb ^ ((r & 7) << 4)));
      }
#pragma unroll
      for (int n = 0; n < 4; ++n)
#pragma unroll
        for (int m = 0; m < 4; ++m) acc[m][n] = MFMA_B16(fa[m], fb[n], acc[m][n]);
    }
    __syncthreads();
  }

  // epilogue: pairs (2p,2p+1) = (g,u) for i = (tn*4 + wc*2 + p)*16 + lr16
#pragma unroll
  for (int m = 0; m < 4; ++m) {
#pragma unroll
    for (int j = 0; j < 4; ++j) {
      const int rl = wr * 64 + m * 16 + hk * 4 + j;
      const int rg = tm * 128 + rl;
      if (rg >= count) continue;
      const size_t drow = listE ? (size_t)listE[rg] : (size_t)(4096 + rg);
      __hip_bfloat16* dh = h + drow * IDIM + (tn * 4 + wc * 2) * 16 + lr16;
#pragma unroll
      for (int p = 0; p < 2; ++p) {
        const float g = acc[m][2 * p][j] * sgc;
        const float u = acc[m][2 * p + 1][j] * suc;
        dh[p * 16] = __float2bfloat16(g / (1.f + __expf(-g)) * u);
      }
    }
  }
}

// ================= down GEMM, 128x128 tile, K=2048, atomicAdd into out =================
// blocks [0,768): experts (e=b/96, tm=(b%96)/6, tn=b%6), A = h[slot]
// blocks [768,864): shared expert, A = h[4096+t]
__global__ __launch_bounds__(256, 3)
void down_kernel(const __hip_bfloat16* __restrict__ h,
                 const __hip_bfloat16* __restrict__ wdT, const __hip_bfloat16* __restrict__ sdT,
                 const float* __restrict__ wt,
                 const int* __restrict__ cnt, const int* __restrict__ lists,
                 float* __restrict__ out)
{
  const int b = blockIdx.x;
  int tm, tn, count;
  const char* bbase;
  const int* listE = nullptr;
  if (b < 768) {
    const int e = b / 96; const int r = b % 96; tm = r / 6; tn = r % 6;
    count = cnt[e];
    if (tm * 128 >= count) return;
    bbase = (const char*)wdT + (size_t)(e * 6 + tn) * (32 * 16384);
    listE = lists + e * TDIM;
  } else {
    const int r = b - 768; tm = r / 6; tn = r % 6;
    count = TDIM;
    bbase = (const char*)sdT + (size_t)tn * (32 * 16384);
  }

  __shared__ __align__(16) char As[16384];
  __shared__ __align__(16) char Bs[16384];

  const int tid = threadIdx.x;
  const int lane = tid & 63;
  const int wid = tid >> 6;
  const int wr = wid >> 1, wc = wid & 1;
  const int lr16 = lane & 15, hk = lane >> 4;

  const int cA = (((lane & 7) ^ (lane >> 3)) << 4);
  const char* aptr[4];
#pragma unroll
  for (int p = 0; p < 4; ++p) {
    const int row = p * 32 + wid * 8 + (lane >> 3);
    const int rg = tm * 128 + row;
    int srow;
    if (listE) { const int idx = rg < count ? rg : count - 1; srow = listE[idx]; }
    else srow = 4096 + rg;
    aptr[p] = (const char*)h + (size_t)srow * (IDIM * 2) + cA;
  }
  const char* bp = bbase + wid * 1024 + lane * 16;

  v4f acc[4][4] = {};

  for (int kt = 0; kt < 32; ++kt) {
#pragma unroll
    for (int p = 0; p < 4; ++p) gload16(aptr[p] + kt * 128, As + wid * 1024 + p * 4096);
#pragma unroll
    for (int p = 0; p < 4; ++p) gload16(bp + kt * 16384 + p * 4096, Bs + wid * 1024 + p * 4096);
    __syncthreads();
#pragma unroll
    for (int ks = 0; ks < 2; ++ks) {
      const int colb = ks * 64 + hk * 16;
      v8bf fa[4], fb[4];
#pragma unroll
      for (int m = 0; m < 4; ++m) {
        const int r = wr * 64 + m * 16 + lr16;
        fa[m] = *(const v8bf*)(As + r * 128 + (colb ^ ((r & 7) << 4)));
      }
#pragma unroll
      for (int n = 0; n < 4; ++n) {
        const int r = wc * 64 + n * 16 + lr16;
        fb[n] = *(const v8bf*)(Bs + r * 128 + (colb ^ ((r & 7) << 4)));
      }
#pragma unroll
      for (int n = 0; n < 4; ++n)
#pragma unroll
        for (int m = 0; m < 4; ++m) acc[m][n] = MFMA_B16(fa[m], fb[n], acc[m][n]);
    }
    __syncthreads();
  }

#pragma unroll
  for (int m = 0; m < 4; ++m) {
#pragma unroll
    for (int j = 0; j < 4; ++j) {
      const int rl = wr * 64 + m * 16 + hk * 4 + j;
      const int rg = tm * 128 + rl;
      if (rg >= count) continue;
      int tok; float w;
      if (listE) { const int slot = listE[rg]; tok = slot >> 1; w = wt[slot]; }  // wt pre-multiplied by sd
      else { tok = rg; w = 1.f; }
      float* dst = out + (size_t)tok * DDIM + tn * 128 + wc * 64 + lr16;
#pragma unroll
      for (int n = 0; n < 4; ++n) atomicAdd(dst + n * 16, acc[m][n][j] * w);
    }
  }
}

extern "C" void kernel_launch(void* const* d_in, const int* in_sizes, int n_in,
                              void* d_out, int out_size, void* d_ws, size_t ws_size,
                              hipStream_t stream)
{
  const float* x   = (const float*)d_in[0];
  const float* rw  = (const float*)d_in[1];
  const float* swg = (const float*)d_in[2];
  const float* swu = (const float*)d_in[3];
  const float* swd = (const float*)d_in[4];
  const int*   qg  = (const int*)d_in[5];
  const int*   qu  = (const int*)d_in[6];
  const int*   qd  = (const int*)d_in[7];
  const float* es  = (const float*)d_in[8];
  float* out = (float*)d_out;

  char* ws = (char*)d_ws;
  size_t off = 0;
  auto alloc = [&](size_t bytes) { void* p = ws + off; off = (off + bytes + 255) & ~(size_t)255; return p; };
  // total ws usage ~= 113 MB
  int*   cnt   = (int*)alloc(NEXP * 4);
  int*   lists = (int*)alloc((size_t)NEXP * TDIM * 4);
  float* wt    = (float*)alloc((size_t)2 * TDIM * 4);
  __hip_bfloat16* xb   = (__hip_bfloat16*)alloc((size_t)TDIM * DDIM * 2);
  __hip_bfloat16* wguT = (__hip_bfloat16*)alloc((size_t)NEXP * 32 * 12 * 8192 * 2);
  __hip_bfloat16* sguT = (__hip_bfloat16*)alloc((size_t)32 * 12 * 8192 * 2);
  __hip_bfloat16* wdT  = (__hip_bfloat16*)alloc((size_t)NEXP * 6 * 32 * 8192 * 2);
  __hip_bfloat16* sdT  = (__hip_bfloat16*)alloc((size_t)6 * 32 * 8192 * 2);
  __hip_bfloat16* h    = (__hip_bfloat16*)alloc((size_t)(4096 + TDIM) * IDIM * 2);

  hipMemsetAsync(cnt, 0, NEXP * 4, stream);
  hipMemsetAsync(out, 0, (size_t)TDIM * DDIM * 4, stream);

  pack_all_kernel<<<6240, 256, 0, stream>>>(qg, qu, qd, swg, swu, swd, x, rw, es,
                                            wguT, sguT, wdT, sdT, xb, cnt, lists, wt);
  gu_gemm_kernel<<<4096 + 512, 256, 0, stream>>>(xb, wguT, sguT, es, cnt, lists, h);
  down_kernel<<<768 + 96, 256, 0, stream>>>(h, wdT, sdT, wt, cnt, lists, out);
}